// Round 5
// baseline (7121.553 us; speedup 1.0000x reference)
//
#include <hip/hip_runtime.h>

typedef unsigned short u16;
typedef unsigned int u32;
typedef __attribute__((ext_vector_type(8))) short bf16x8;
typedef __attribute__((ext_vector_type(4))) float f32x4;
typedef __attribute__((ext_vector_type(4))) u32 u32x4;
typedef const __attribute__((address_space(1))) void* gas1_t;
typedef __attribute__((address_space(3))) void* las3_t;

// Problem dims
#define T_LEN 512
#define B_SZ  64
#define D_SZ  1024
#define H_SZ  1024

// workspace layout (bytes), all 256-aligned
#define OFF_WX    0UL           // 8 MiB  bf16 Wx  [4096][1024]
#define OFF_WH    8388608UL     // 8 MiB  bf16 Wh  [4096][1024]
#define OFF_BIAS  16777216UL    // 16 KiB f32 bias[4096] = bx+bh
#define OFF_FLAGS 16793600UL    // 4 KiB  u32 flags[1024] (per-wave, 2 half-domains)
#define OFF_HBUF  16797696UL    // 256 KiB bf16 hbuf[2][64][1024]
#define OFF_XBF   17059840UL    // 64 MiB bf16 x [32768][1024]
#define OFF_XPROJ 84168704UL    // 256 MiB bf16 xproj [32768][4096]

__device__ __forceinline__ u16 f2bf(float f) {
  u32 u = __builtin_bit_cast(u32, f);
  u += 0x7FFFu + ((u >> 16) & 1u);   // RNE
  return (u16)(u >> 16);
}
__device__ __forceinline__ float bf2f(u16 h) {
  u32 u = ((u32)h) << 16;
  return __builtin_bit_cast(float, u);
}

// ---------- phase 0: conversions ----------
__global__ __launch_bounds__(256) void cvt_f32_bf16(const float* __restrict__ in,
                                                    u16* __restrict__ out, int n) {
  int i = (blockIdx.x * 256 + threadIdx.x) * 4;
  if (i >= n) return;
  float4 v = *(const float4*)(in + i);
  ushort4 o;
  o.x = f2bf(v.x); o.y = f2bf(v.y); o.z = f2bf(v.z); o.w = f2bf(v.w);
  *(ushort4*)(out + i) = o;
}

__global__ __launch_bounds__(256) void bias_add(const float* __restrict__ a,
                                                const float* __restrict__ b,
                                                float* __restrict__ o) {
  int i = blockIdx.x * 256 + threadIdx.x;  // 4096 total
  o[i] = a[i] + b[i];
}

// ---------- phase 1: xproj = x @ Wx^T (bf16 MFMA, 128x128 tile, BK=64) ----------
__global__ __launch_bounds__(256) void gemm_xproj(const u16* __restrict__ A,
                                                  const u16* __restrict__ Bw,
                                                  u16* __restrict__ C) {
  __shared__ __align__(16) u16 As[128 * 64];
  __shared__ __align__(16) u16 Bs[128 * 64];
  int wg = blockIdx.x;
  int swz = (wg & 7) * 1024 + (wg >> 3);  // XCD-aware bijective (8192 % 8 == 0)
  int mb = swz >> 5;
  int nb = swz & 31;
  int tid = threadIdx.x;
  int lane = tid & 63;
  int w = tid >> 6;
  int wm = w >> 1, wn = w & 1;

  int srow = lane >> 3;
  int scol = (lane & 7) * 8;
  const u16* Abase = A + (size_t)(mb * 128) * 1024;
  const u16* Bbase = Bw + (size_t)(nb * 128) * 1024;

  f32x4 acc[4][4];
#pragma unroll
  for (int i = 0; i < 4; ++i)
#pragma unroll
    for (int j = 0; j < 4; ++j) acc[i][j] = f32x4{0.f, 0.f, 0.f, 0.f};

  for (int k0 = 0; k0 < 1024; k0 += 64) {
#pragma unroll
    for (int r = 0; r < 4; ++r) {
      int chunk = w * 4 + r;
      int row = chunk * 8 + srow;
      __builtin_amdgcn_global_load_lds((gas1_t)(const void*)(Abase + (size_t)row * 1024 + k0 + scol),
                                       (las3_t)(void*)(&As[chunk * 512]), 16, 0, 0);
      __builtin_amdgcn_global_load_lds((gas1_t)(const void*)(Bbase + (size_t)row * 1024 + k0 + scol),
                                       (las3_t)(void*)(&Bs[chunk * 512]), 16, 0, 0);
    }
    __syncthreads();
#pragma unroll
    for (int kk = 0; kk < 64; kk += 32) {
      bf16x8 af[4], bfr[4];
#pragma unroll
      for (int mt = 0; mt < 4; ++mt)
        af[mt] = *(const bf16x8*)&As[(wm * 64 + mt * 16 + (lane & 15)) * 64 + kk + ((lane >> 4) << 3)];
#pragma unroll
      for (int nt = 0; nt < 4; ++nt)
        bfr[nt] = *(const bf16x8*)&Bs[(wn * 64 + nt * 16 + (lane & 15)) * 64 + kk + ((lane >> 4) << 3)];
#pragma unroll
      for (int mt = 0; mt < 4; ++mt)
#pragma unroll
        for (int nt = 0; nt < 4; ++nt)
          acc[mt][nt] = __builtin_amdgcn_mfma_f32_16x16x32_bf16(af[mt], bfr[nt], acc[mt][nt], 0, 0, 0);
    }
    __syncthreads();
  }
  int crowbase = mb * 128 + wm * 64;
  int ccolbase = nb * 128 + wn * 64;
#pragma unroll
  for (int mt = 0; mt < 4; ++mt)
#pragma unroll
    for (int nt = 0; nt < 4; ++nt) {
      int col = ccolbase + nt * 16 + (lane & 15);
#pragma unroll
      for (int r = 0; r < 4; ++r) {
        int row = crowbase + mt * 16 + ((lane >> 4) << 2) + r;
        C[(size_t)row * 4096 + col] = f2bf(acc[mt][nt][r]);
      }
    }
}

// ---------- phase 2: persistent sequential LSTM ----------
// 128 WGs x 512 threads. WG = (bh, hw): batch-half bh (32 rows) x 16 h-cols.
// 8 waves = 2 col-groups x 4 K-slices. Wh register-resident. Two independent
// 64-WG barrier domains. Per-WAVE flags (plain sc0 sc1 stores, no atomics);
// every wave drains its own stores (counted vmcnt) and polls independently --
// no __syncthreads on the barrier path (only 2 intra-WG syncs around the LDS
// reduce). xproj for t+1 prefetched under the poll wait (issue after h store,
// vmcnt(4) so store drain doesn't wait on it; poll asm "+v"-ties the regs).
__global__ __launch_bounds__(512) void lstm_seq(const u16* __restrict__ xproj,
                                                const u16* __restrict__ Whb,
                                                const float* __restrict__ bias,
                                                u16* __restrict__ hbuf,
                                                u32* __restrict__ flags,
                                                float* __restrict__ out) {
  __shared__ float pacc[32 * 272];  // 32 frags, rows padded to 17 floats
#define PIDX(frag, row, col) (((frag) * 272) + (row) * 17 + (col))
  int wg = blockIdx.x;     // 0..127
  int bh = wg >> 6;        // batch half (independent barrier domain)
  int hw = wg & 63;        // 16-col slice index
  int tid = threadIdx.x;   // 0..511
  int lane = tid & 63;
  int w = tid >> 6;        // 0..7
  int cg = w >> 2;         // col-group (8 cols each)
  int kq = w & 3;          // K-slice
  int kw = kq << 8;        // k base (256 per K-slice)
  int hs = (hw << 1) + cg; // effective 8-col slice 0..127
  int hi8 = (lane >> 4) << 3;

  // preload Wh fragments (register-resident for all 512 steps)
  bf16x8 wf[2][8];
#pragma unroll
  for (int nt = 0; nt < 2; ++nt) {
    int c = nt * 16 + (lane & 15);
    int wrow = ((c >> 3) << 10) + (hs << 3) + (c & 7);  // gate*1024 + hs*8 + jcol
#pragma unroll
    for (int ks = 0; ks < 8; ++ks)
      wf[nt][ks] = *(const bf16x8*)&Whb[(size_t)wrow * 1024 + kw + ks * 32 + hi8];
  }

  int b = tid >> 4;                  // 0..31 batch row within half
  int jj = tid & 15;                 // 0..15 h-col within WG slice
  int cgj = jj >> 3;                 // col-group of this thread's column
  int jcol = jj & 7;
  int hrow = (bh << 5) + b;
  int hcol = (hw << 4) + jj;
  float bs0 = bias[hcol], bs1 = bias[1024 + hcol], bs2 = bias[2048 + hcol], bs3 = bias[3072 + hcol];
  float c_state = 0.f;
  int am_row0 = (bh << 5) + (lane & 15);
  int am_row1 = am_row0 + 16;
  int mI = b >> 4, r16 = b & 15;
  u32* fbase = flags + (bh << 9);            // this half's 512 per-wave flags
  u32* myflag = fbase + (hw << 3) + w;       // this wave's flag
  const u32* pollp = fbase + (lane << 3);    // 8 flags per lane

  // rolling xproj pointers (gates 0/1 via xa0+{0,2048B}, gates 2/3 via xa1)
  const u16* xa0 = xproj + (size_t)hrow * 4096 + hcol;
  const u16* xa1 = xa0 + 2048;
  // t=0 xproj prefetch (plain cached loads)
  u32 px0 = xa0[0], px1 = xa0[1024], px2 = xa1[0], px3 = xa1[1024];

  for (int t = 0; t < T_LEN; ++t) {
    const u16* hcur = hbuf + (size_t)(t & 1) * 65536;
    // --- coherent h load: 16x dwordx4 sc0 sc1 + vmcnt(0) in ONE asm ---
    const u16* p0 = hcur + (size_t)am_row0 * 1024 + kw + hi8;
    const u16* p1 = hcur + (size_t)am_row1 * 1024 + kw + hi8;
    u32x4 r0, r1, r2, r3, r4, r5, r6, r7, r8, r9, r10, r11, r12, r13, r14, r15;
    asm volatile(
        "global_load_dwordx4 %0, %16, off sc0 sc1\n\t"
        "global_load_dwordx4 %1, %16, off offset:64 sc0 sc1\n\t"
        "global_load_dwordx4 %2, %16, off offset:128 sc0 sc1\n\t"
        "global_load_dwordx4 %3, %16, off offset:192 sc0 sc1\n\t"
        "global_load_dwordx4 %4, %16, off offset:256 sc0 sc1\n\t"
        "global_load_dwordx4 %5, %16, off offset:320 sc0 sc1\n\t"
        "global_load_dwordx4 %6, %16, off offset:384 sc0 sc1\n\t"
        "global_load_dwordx4 %7, %16, off offset:448 sc0 sc1\n\t"
        "global_load_dwordx4 %8, %17, off sc0 sc1\n\t"
        "global_load_dwordx4 %9, %17, off offset:64 sc0 sc1\n\t"
        "global_load_dwordx4 %10, %17, off offset:128 sc0 sc1\n\t"
        "global_load_dwordx4 %11, %17, off offset:192 sc0 sc1\n\t"
        "global_load_dwordx4 %12, %17, off offset:256 sc0 sc1\n\t"
        "global_load_dwordx4 %13, %17, off offset:320 sc0 sc1\n\t"
        "global_load_dwordx4 %14, %17, off offset:384 sc0 sc1\n\t"
        "global_load_dwordx4 %15, %17, off offset:448 sc0 sc1\n\t"
        "s_waitcnt vmcnt(0)"
        : "=&v"(r0), "=&v"(r1), "=&v"(r2), "=&v"(r3),
          "=&v"(r4), "=&v"(r5), "=&v"(r6), "=&v"(r7),
          "=&v"(r8), "=&v"(r9), "=&v"(r10), "=&v"(r11),
          "=&v"(r12), "=&v"(r13), "=&v"(r14), "=&v"(r15)
        : "v"(p0), "v"(p1)
        : "memory");
    bf16x8 a0s[8] = {__builtin_bit_cast(bf16x8, r0),  __builtin_bit_cast(bf16x8, r1),
                     __builtin_bit_cast(bf16x8, r2),  __builtin_bit_cast(bf16x8, r3),
                     __builtin_bit_cast(bf16x8, r4),  __builtin_bit_cast(bf16x8, r5),
                     __builtin_bit_cast(bf16x8, r6),  __builtin_bit_cast(bf16x8, r7)};
    bf16x8 a1s[8] = {__builtin_bit_cast(bf16x8, r8),  __builtin_bit_cast(bf16x8, r9),
                     __builtin_bit_cast(bf16x8, r10), __builtin_bit_cast(bf16x8, r11),
                     __builtin_bit_cast(bf16x8, r12), __builtin_bit_cast(bf16x8, r13),
                     __builtin_bit_cast(bf16x8, r14), __builtin_bit_cast(bf16x8, r15)};

    f32x4 acc00 = f32x4{0.f, 0.f, 0.f, 0.f}, acc01 = acc00, acc10 = acc00, acc11 = acc00;
#pragma unroll
    for (int ks = 0; ks < 8; ++ks) {
      acc00 = __builtin_amdgcn_mfma_f32_16x16x32_bf16(a0s[ks], wf[0][ks], acc00, 0, 0, 0);
      acc01 = __builtin_amdgcn_mfma_f32_16x16x32_bf16(a0s[ks], wf[1][ks], acc01, 0, 0, 0);
      acc10 = __builtin_amdgcn_mfma_f32_16x16x32_bf16(a1s[ks], wf[0][ks], acc10, 0, 0, 0);
      acc11 = __builtin_amdgcn_mfma_f32_16x16x32_bf16(a1s[ks], wf[1][ks], acc11, 0, 0, 0);
    }
    // per-wave partials -> LDS: frag = cg*16 + kq*4 + m*2 + nt
    {
      int rbase = ((lane >> 4) << 2);
      int cidx = lane & 15;
      int f0i = (cg << 4) + (kq << 2);
#pragma unroll
      for (int r = 0; r < 4; ++r) {
        pacc[PIDX(f0i + 0, rbase + r, cidx)] = acc00[r];
        pacc[PIDX(f0i + 1, rbase + r, cidx)] = acc01[r];
        pacc[PIDX(f0i + 2, rbase + r, cidx)] = acc10[r];
        pacc[PIDX(f0i + 3, rbase + r, cidx)] = acc11[r];
      }
    }
    __syncthreads();
    float g[4];
#pragma unroll
    for (int gate = 0; gate < 4; ++gate) {
      int c = gate * 8 + jcol;
      int nt = c >> 4, c16 = c & 15;
      float s = 0.f;
#pragma unroll
      for (int k2 = 0; k2 < 4; ++k2)
        s += pacc[PIDX((cgj << 4) + (k2 << 2) + (mI << 1) + nt, r16, c16)];
      g[gate] = s;
    }
    __syncthreads();  // pacc reads done before next iteration's writes
    float gi = g[0] + bf2f((u16)px0) + bs0;
    float gf = g[1] + bf2f((u16)px1) + bs1;
    float go = g[2] + bf2f((u16)px2) + bs2;
    float gc = g[3] + bf2f((u16)px3) + bs3;
    float iv = 1.f / (1.f + __expf(-gi));
    float fv = 1.f / (1.f + __expf(-gf));
    float ov = 1.f / (1.f + __expf(-go));
    float cv = tanhf(gc);
    c_state = 1.f / (1.f + __expf(-(fv * c_state + iv * cv)));  // nonstandard, per reference
    float hn = tanhf(c_state) * ov;

    if (t == T_LEN - 1) {
      out[(size_t)hrow * 1024 + hcol] = hn;
    } else {
      // h store (write-through to LLC) + issue t+1 xproj prefetch + counted drain:
      // vmcnt(4) waits the store (oldest) while the 4 prefetch loads stay in flight.
      u16* hdst = hbuf + (size_t)((t & 1) ^ 1) * 65536 + (size_t)hrow * 1024 + hcol;
      u32 hb = (u32)f2bf(hn);
      xa0 += 262144;  // advance one timestep (64 rows * 4096)
      xa1 += 262144;
      asm volatile(
          "global_store_short %4, %6, off sc0 sc1\n\t"
          "global_load_ushort %0, %5, off\n\t"
          "global_load_ushort %1, %5, off offset:2048\n\t"
          "global_load_ushort %2, %7, off\n\t"
          "global_load_ushort %3, %7, off offset:2048\n\t"
          "s_waitcnt vmcnt(4)"
          : "=&v"(px0), "=&v"(px1), "=&v"(px2), "=&v"(px3)
          : "v"(hdst), "v"(xa0), "v"(hb), "v"(xa1)
          : "memory");
      // per-wave flag publish (plain dword store, no RMW)
      u32 tgt = (u32)(t + 1);
      if (lane == 0)
        asm volatile("global_store_dword %0, %1, off sc0 sc1" :: "v"(myflag), "v"(tgt) : "memory");
      // every wave polls its half's 512 flags independently; "+v" ties px so the
      // compiler can't consume the prefetch results before a vmcnt(0) executes.
      for (;;) {
        u32x4 f0, f1;
        asm volatile(
            "global_load_dwordx4 %0, %6, off sc0 sc1\n\t"
            "global_load_dwordx4 %1, %6, off offset:16 sc0 sc1\n\t"
            "s_waitcnt vmcnt(0)"
            : "=&v"(f0), "=&v"(f1), "+v"(px0), "+v"(px1), "+v"(px2), "+v"(px3)
            : "v"(pollp)
            : "memory");
        bool ok = (f0[0] >= tgt) && (f0[1] >= tgt) && (f0[2] >= tgt) && (f0[3] >= tgt) &&
                  (f1[0] >= tgt) && (f1[1] >= tgt) && (f1[2] >= tgt) && (f1[3] >= tgt);
        if (__all(ok)) break;
      }
    }
  }
}

extern "C" void kernel_launch(void* const* d_in, const int* in_sizes, int n_in,
                              void* d_out, int out_size, void* d_ws, size_t ws_size,
                              hipStream_t stream) {
  const float* x  = (const float*)d_in[0];   // [512][64][1024]
  const float* Wx = (const float*)d_in[1];   // [4][1024][1024]
  const float* bx = (const float*)d_in[2];   // [4][1024]
  const float* Wh = (const float*)d_in[3];   // [4][1024][1024]
  const float* bh = (const float*)d_in[4];   // [4][1024]
  float* out = (float*)d_out;                // [64][1024]
  char* ws = (char*)d_ws;

  u16* wx_bf  = (u16*)(ws + OFF_WX);
  u16* wh_bf  = (u16*)(ws + OFF_WH);
  float* bias = (float*)(ws + OFF_BIAS);
  u32* flags  = (u32*)(ws + OFF_FLAGS);
  u16* hbuf   = (u16*)(ws + OFF_HBUF);
  u16* x_bf   = (u16*)(ws + OFF_XBF);
  u16* xproj  = (u16*)(ws + OFF_XPROJ);

  // zero flags (4 KiB) + hbuf slot 0 (h_0 = 0, 128 KiB) -- contiguous
  hipMemsetAsync(ws + OFF_FLAGS, 0, 4096 + 131072, stream);

  cvt_f32_bf16<<<4096, 256, 0, stream>>>(Wx, wx_bf, 4194304);
  cvt_f32_bf16<<<4096, 256, 0, stream>>>(Wh, wh_bf, 4194304);
  bias_add<<<16, 256, 0, stream>>>(bx, bh, bias);
  cvt_f32_bf16<<<32768, 256, 0, stream>>>(x, x_bf, 33554432);
  gemm_xproj<<<8192, 256, 0, stream>>>(x_bf, wx_bf, xproj);
  lstm_seq<<<128, 512, 0, stream>>>(xproj, wh_bf, bias, hbuf, flags, out);
}

// Round 6
// 5242.563 us; speedup vs baseline: 1.3584x; 1.3584x over previous
//
#include <hip/hip_runtime.h>

typedef unsigned short u16;
typedef unsigned int u32;
typedef __attribute__((ext_vector_type(8))) short bf16x8;
typedef __attribute__((ext_vector_type(4))) float f32x4;
typedef __attribute__((ext_vector_type(2))) u32 u32x2;
typedef const __attribute__((address_space(1))) void* gas1_t;
typedef __attribute__((address_space(3))) void* las3_t;

// Problem dims
#define T_LEN 512
#define B_SZ  64
#define D_SZ  1024
#define H_SZ  1024

// workspace layout (bytes), all 256-aligned
#define OFF_WX    0UL           // 8 MiB  bf16 Wx  [4096][1024]
#define OFF_WH    8388608UL     // 8 MiB  bf16 Wh  [4096][1024]
#define OFF_BIAS  16777216UL    // 16 KiB f32 bias[4096] = bx+bh
#define OFF_FLAGS 16793600UL    // 1 KiB  u32 flags[2][128]
#define OFF_HROLL 16794624UL    // 64 MiB bf16 hroll[512][64][1024] (slot t = h input of step t)
#define OFF_XBF   83903488UL    // 64 MiB bf16 x [32768][1024]
#define OFF_XPROJ 151012352UL   // 256 MiB bf16 xprojP [512][128][64][8][4] ([t][hs][brow][jj][gate])

__device__ __forceinline__ u16 f2bf(float f) {
  u32 u = __builtin_bit_cast(u32, f);
  u += 0x7FFFu + ((u >> 16) & 1u);   // RNE
  return (u16)(u >> 16);
}
__device__ __forceinline__ float bf2f(u16 h) {
  u32 u = ((u32)h) << 16;
  return __builtin_bit_cast(float, u);
}

// ---------- phase 0: conversions ----------
__global__ __launch_bounds__(256) void cvt_f32_bf16(const float* __restrict__ in,
                                                    u16* __restrict__ out, int n) {
  int i = (blockIdx.x * 256 + threadIdx.x) * 4;
  if (i >= n) return;
  float4 v = *(const float4*)(in + i);
  ushort4 o;
  o.x = f2bf(v.x); o.y = f2bf(v.y); o.z = f2bf(v.z); o.w = f2bf(v.w);
  *(ushort4*)(out + i) = o;
}

__global__ __launch_bounds__(256) void bias_add(const float* __restrict__ a,
                                                const float* __restrict__ b,
                                                float* __restrict__ o) {
  int i = blockIdx.x * 256 + threadIdx.x;  // 4096 total
  o[i] = a[i] + b[i];
}

// ---------- phase 1: xproj = x @ Wx^T, written PERMUTED for the lstm reader ----------
// C layout: [t(512)][hs(128)][brow(64)][jj(8)][gate(4)] -- each lstm WG's
// per-step read is 2 KB contiguous; each thread one dwordx2 (4 gates).
__global__ __launch_bounds__(256) void gemm_xproj(const u16* __restrict__ A,
                                                  const u16* __restrict__ Bw,
                                                  u16* __restrict__ C) {
  __shared__ __align__(16) u16 As[128 * 64];
  __shared__ __align__(16) u16 Bs[128 * 64];
  int wg = blockIdx.x;
  int swz = (wg & 7) * 1024 + (wg >> 3);  // XCD-aware bijective (8192 % 8 == 0)
  int mb = swz >> 5;
  int nb = swz & 31;
  int tid = threadIdx.x;
  int lane = tid & 63;
  int w = tid >> 6;
  int wm = w >> 1, wn = w & 1;

  int srow = lane >> 3;
  int scol = (lane & 7) * 8;
  const u16* Abase = A + (size_t)(mb * 128) * 1024;
  const u16* Bbase = Bw + (size_t)(nb * 128) * 1024;

  f32x4 acc[4][4];
#pragma unroll
  for (int i = 0; i < 4; ++i)
#pragma unroll
    for (int j = 0; j < 4; ++j) acc[i][j] = f32x4{0.f, 0.f, 0.f, 0.f};

  for (int k0 = 0; k0 < 1024; k0 += 64) {
#pragma unroll
    for (int r = 0; r < 4; ++r) {
      int chunk = w * 4 + r;
      int row = chunk * 8 + srow;
      __builtin_amdgcn_global_load_lds((gas1_t)(const void*)(Abase + (size_t)row * 1024 + k0 + scol),
                                       (las3_t)(void*)(&As[chunk * 512]), 16, 0, 0);
      __builtin_amdgcn_global_load_lds((gas1_t)(const void*)(Bbase + (size_t)row * 1024 + k0 + scol),
                                       (las3_t)(void*)(&Bs[chunk * 512]), 16, 0, 0);
    }
    __syncthreads();
#pragma unroll
    for (int kk = 0; kk < 64; kk += 32) {
      bf16x8 af[4], bfr[4];
#pragma unroll
      for (int mt = 0; mt < 4; ++mt)
        af[mt] = *(const bf16x8*)&As[(wm * 64 + mt * 16 + (lane & 15)) * 64 + kk + ((lane >> 4) << 3)];
#pragma unroll
      for (int nt = 0; nt < 4; ++nt)
        bfr[nt] = *(const bf16x8*)&Bs[(wn * 64 + nt * 16 + (lane & 15)) * 64 + kk + ((lane >> 4) << 3)];
#pragma unroll
      for (int mt = 0; mt < 4; ++mt)
#pragma unroll
        for (int nt = 0; nt < 4; ++nt)
          acc[mt][nt] = __builtin_amdgcn_mfma_f32_16x16x32_bf16(af[mt], bfr[nt], acc[mt][nt], 0, 0, 0);
    }
    __syncthreads();
  }
  int crowbase = mb * 128 + wm * 64;
  int ccolbase = nb * 128 + wn * 64;
#pragma unroll
  for (int mt = 0; mt < 4; ++mt)
#pragma unroll
    for (int nt = 0; nt < 4; ++nt) {
      int col = ccolbase + nt * 16 + (lane & 15);
      int gate = col >> 10;
      int hc = col & 1023;
      size_t cb = (size_t)(hc >> 3) * 2048 + (size_t)(hc & 7) * 4 + gate;  // hs*64*32 + jj*4 + gate
#pragma unroll
      for (int r = 0; r < 4; ++r) {
        int row = crowbase + mt * 16 + ((lane >> 4) << 2) + r;
        C[(size_t)(row >> 6) * 262144 + cb + (size_t)(row & 63) * 32] = f2bf(acc[mt][nt][r]);
      }
    }
}

// ---------- phase 2: persistent sequential LSTM ----------
// R2-proven lean protocol + three fixes:
//  (1) ROLLING h buffer: slot t written once per launch (step t-1), read after
//      the step-(t-1) barrier -> NORMAL CACHED h loads are staleness-safe
//      (virgin addresses; dispatch-boundary acquire handles cross-launch).
//      Per-XCD L2 dedup kills the 16 MB/step uncached LLC read storm.
//  (2) permuted xproj: one dwordx2 per thread, full-line utilization.
//  (3) xproj(t+1) prefetched in the same asm as the h store; vmcnt(1) drains
//      the (older, in-order) store while the load flies through the poll.
// h stores: per-thread write-through sc0 sc1 (L2 never dirty -> no wbl2).
__global__ __launch_bounds__(256) void lstm_seq(const u16* __restrict__ xprojP,
                                                const u16* __restrict__ Whb,
                                                const float* __restrict__ bias,
                                                u16* __restrict__ hroll,
                                                u32* __restrict__ flags,
                                                float* __restrict__ out) {
  __shared__ float pacc[16 * 272];  // rows padded to 17 floats
#define PIDX(frag, row, col) (((frag) * 272) + (row) * 17 + (col))
  int wg = blockIdx.x;
  int bh = wg >> 7;       // batch half (independent barrier domain)
  int hs = wg & 127;      // 8-col h slice
  int tid = threadIdx.x;
  int lane = tid & 63;
  int w = tid >> 6;       // wave -> K-slice
  int kw = w << 8;        // k base (256 per wave)
  int hi8 = (lane >> 4) << 3;

  // preload Wh fragments (register-resident for all 512 steps)
  bf16x8 wf[2][8];
#pragma unroll
  for (int nt = 0; nt < 2; ++nt) {
    int c = nt * 16 + (lane & 15);
    int wrow = ((c >> 3) << 10) + (hs << 3) + (c & 7);  // gate*1024 + hs*8 + jj
#pragma unroll
    for (int ks = 0; ks < 8; ++ks)
      wf[nt][ks] = *(const bf16x8*)&Whb[(size_t)wrow * 1024 + kw + ks * 32 + hi8];
  }

  int b = tid >> 3;                  // 0..31 batch row within half
  int jj = tid & 7;                  // h-col within slice
  int hrow = (bh << 5) + b;
  int hcol = (hs << 3) + jj;
  float bs0 = bias[hcol], bs1 = bias[1024 + hcol], bs2 = bias[2048 + hcol], bs3 = bias[3072 + hcol];
  float c_state = 0.f;
  int am_row0 = (bh << 5) + (lane & 15);
  int am_row1 = am_row0 + 16;
  int mI = b >> 4, r16 = b & 15;
  u32* myflags = flags + (bh << 7);  // 128 dwords for this half

  // permuted xproj pointer for this thread; per-step stride 262144 elems (512 KB)
  const u16* xpt = xprojP + ((size_t)hs * 64 + hrow) * 32 + jj * 4;
  u32x2 pd = *(const u32x2*)xpt;     // t=0 prefetch (plain cached)

  for (int t = 0; t < T_LEN; ++t) {
    // h loads: NORMAL CACHED from rolling slot t (L2-dedup'd per XCD)
    const u16* hcur = hroll + (size_t)t * 65536;
    const u16* p0 = hcur + (size_t)am_row0 * 1024 + kw + hi8;
    const u16* p1 = hcur + (size_t)am_row1 * 1024 + kw + hi8;
    bf16x8 a0s[8], a1s[8];
#pragma unroll
    for (int ks = 0; ks < 8; ++ks) {
      a0s[ks] = *(const bf16x8*)(p0 + ks * 32);
      a1s[ks] = *(const bf16x8*)(p1 + ks * 32);
    }

    f32x4 acc00 = f32x4{0.f, 0.f, 0.f, 0.f}, acc01 = acc00, acc10 = acc00, acc11 = acc00;
#pragma unroll
    for (int ks = 0; ks < 8; ++ks) {
      acc00 = __builtin_amdgcn_mfma_f32_16x16x32_bf16(a0s[ks], wf[0][ks], acc00, 0, 0, 0);
      acc01 = __builtin_amdgcn_mfma_f32_16x16x32_bf16(a0s[ks], wf[1][ks], acc01, 0, 0, 0);
      acc10 = __builtin_amdgcn_mfma_f32_16x16x32_bf16(a1s[ks], wf[0][ks], acc10, 0, 0, 0);
      acc11 = __builtin_amdgcn_mfma_f32_16x16x32_bf16(a1s[ks], wf[1][ks], acc11, 0, 0, 0);
    }
    // per-wave partials -> LDS (padded)
    {
      int rbase = ((lane >> 4) << 2);
      int cidx = lane & 15;
#pragma unroll
      for (int r = 0; r < 4; ++r) {
        pacc[PIDX(w * 4 + 0, rbase + r, cidx)] = acc00[r];
        pacc[PIDX(w * 4 + 1, rbase + r, cidx)] = acc01[r];
        pacc[PIDX(w * 4 + 2, rbase + r, cidx)] = acc10[r];
        pacc[PIDX(w * 4 + 3, rbase + r, cidx)] = acc11[r];
      }
    }
    __syncthreads();
    float g[4];
#pragma unroll
    for (int gate = 0; gate < 4; ++gate) {
      int cc = gate * 8 + jj;
      int nt = cc >> 4, c16 = cc & 15;
      float s = 0.f;
#pragma unroll
      for (int w2 = 0; w2 < 4; ++w2)
        s += pacc[PIDX(w2 * 4 + mI * 2 + nt, r16, c16)];
      g[gate] = s;
    }
    // tie the prefetched xproj dwords to a vmcnt before use (rule #18)
    asm volatile("s_waitcnt vmcnt(0)" : "+v"(pd));
    float gi = g[0] + bf2f((u16)(pd[0] & 0xFFFFu)) + bs0;
    float gf = g[1] + bf2f((u16)(pd[0] >> 16)) + bs1;
    float go = g[2] + bf2f((u16)(pd[1] & 0xFFFFu)) + bs2;
    float gc = g[3] + bf2f((u16)(pd[1] >> 16)) + bs3;
    float iv = 1.f / (1.f + __expf(-gi));
    float fv = 1.f / (1.f + __expf(-gf));
    float ov = 1.f / (1.f + __expf(-go));
    float cv = tanhf(gc);
    c_state = 1.f / (1.f + __expf(-(fv * c_state + iv * cv)));  // nonstandard, per reference
    float hn = tanhf(c_state) * ov;

    if (t == T_LEN - 1) {
      out[(size_t)hrow * 1024 + hcol] = hn;
    } else {
      // h store (write-through) + xproj(t+1) prefetch + in-order counted drain:
      // vmcnt(1) retires the OLDER store; the load stays in flight through the poll.
      u16* hdst = hroll + (size_t)(t + 1) * 65536 + (size_t)hrow * 1024 + hcol;
      const u16* xnext = xpt + (size_t)(t + 1) * 262144;
      u32 hb = (u32)f2bf(hn);
      asm volatile(
          "global_store_short %1, %3, off sc0 sc1\n\t"
          "global_load_dwordx2 %0, %2, off\n\t"
          "s_waitcnt vmcnt(1)"
          : "=&v"(pd)
          : "v"(hdst), "v"(xnext), "v"(hb)
          : "memory");
      __syncthreads();  // all waves' stores drained; pacc reads done
      u32 tgt = (u32)(t + 1);
      if (tid == 0) {
        u32* fp = myflags + hs;
        asm volatile("global_store_dword %0, %1, off sc0 sc1" :: "v"(fp), "v"(tgt) : "memory");
      }
      if (tid < 64) {
        const u32* fp = myflags + (tid << 1);
        for (;;) {
          u32x2 f;
          asm volatile("global_load_dwordx2 %0, %1, off sc0 sc1\n\ts_waitcnt vmcnt(0)"
                       : "=v"(f) : "v"(fp) : "memory");
          if (__all((f[0] >= tgt) && (f[1] >= tgt))) break;
        }
      }
      __syncthreads();
    }
  }
}

extern "C" void kernel_launch(void* const* d_in, const int* in_sizes, int n_in,
                              void* d_out, int out_size, void* d_ws, size_t ws_size,
                              hipStream_t stream) {
  const float* x  = (const float*)d_in[0];   // [512][64][1024]
  const float* Wx = (const float*)d_in[1];   // [4][1024][1024]
  const float* bx = (const float*)d_in[2];   // [4][1024]
  const float* Wh = (const float*)d_in[3];   // [4][1024][1024]
  const float* bh = (const float*)d_in[4];   // [4][1024]
  float* out = (float*)d_out;                // [64][1024]
  char* ws = (char*)d_ws;

  u16* wx_bf  = (u16*)(ws + OFF_WX);
  u16* wh_bf  = (u16*)(ws + OFF_WH);
  float* bias = (float*)(ws + OFF_BIAS);
  u32* flags  = (u32*)(ws + OFF_FLAGS);
  u16* hroll  = (u16*)(ws + OFF_HROLL);
  u16* x_bf   = (u16*)(ws + OFF_XBF);
  u16* xproj  = (u16*)(ws + OFF_XPROJ);

  // per-launch: zero flags (1 KiB) + rolling slot 0 (h_0 = 0, 128 KiB) -- contiguous
  hipMemsetAsync(ws + OFF_FLAGS, 0, 1024 + 131072, stream);

  cvt_f32_bf16<<<4096, 256, 0, stream>>>(Wx, wx_bf, 4194304);
  cvt_f32_bf16<<<4096, 256, 0, stream>>>(Wh, wh_bf, 4194304);
  bias_add<<<16, 256, 0, stream>>>(bx, bh, bias);
  cvt_f32_bf16<<<32768, 256, 0, stream>>>(x, x_bf, 33554432);
  gemm_xproj<<<8192, 256, 0, stream>>>(x_bf, wx_bf, xproj);
  lstm_seq<<<256, 256, 0, stream>>>(xproj, wh_bf, bias, hroll, flags, out);
}

// Round 8
// 4596.437 us; speedup vs baseline: 1.5494x; 1.1406x over previous
//
#include <hip/hip_runtime.h>

typedef unsigned short u16;
typedef unsigned int u32;
typedef __attribute__((ext_vector_type(8))) short bf16x8;
typedef __attribute__((ext_vector_type(4))) float f32x4;
typedef __attribute__((ext_vector_type(2))) u32 u32x2;
typedef __attribute__((ext_vector_type(4))) u32 u32x4;
typedef const __attribute__((address_space(1))) void* gas1_t;
typedef __attribute__((address_space(3))) void* las3_t;

// Problem dims
#define T_LEN 512
#define B_SZ  64
#define D_SZ  1024
#define H_SZ  1024

// workspace layout (bytes), all 256-aligned
#define OFF_WX    0UL           // 8 MiB  bf16 Wx  [4096][1024]
#define OFF_WH    8388608UL     // 8 MiB  bf16 Wh  [4096][1024]
#define OFF_BIAS  16777216UL    // 16 KiB f32 bias[4096] = bx+bh
#define OFF_FLAGS 16793600UL    // 1 KiB  u32 flags[2][64]
#define OFF_HBUF  16794624UL    // 256 KiB bf16 hbuf[2][64][1024]
#define OFF_XBF   17056768UL    // 64 MiB bf16 x [32768][1024]
#define OFF_XPROJ 84165632UL    // 256 MiB bf16 xprojP [512][128][64][8][4] ([t][hs][brow][jj][gate])

__device__ __forceinline__ u16 f2bf(float f) {
  u32 u = __builtin_bit_cast(u32, f);
  u += 0x7FFFu + ((u >> 16) & 1u);   // RNE
  return (u16)(u >> 16);
}
__device__ __forceinline__ float bf2f(u16 h) {
  u32 u = ((u32)h) << 16;
  return __builtin_bit_cast(float, u);
}

// ---------- phase 0: conversions ----------
__global__ __launch_bounds__(256) void cvt_f32_bf16(const float* __restrict__ in,
                                                    u16* __restrict__ out, int n) {
  int i = (blockIdx.x * 256 + threadIdx.x) * 4;
  if (i >= n) return;
  float4 v = *(const float4*)(in + i);
  ushort4 o;
  o.x = f2bf(v.x); o.y = f2bf(v.y); o.z = f2bf(v.z); o.w = f2bf(v.w);
  *(ushort4*)(out + i) = o;
}

__global__ __launch_bounds__(256) void bias_add(const float* __restrict__ a,
                                                const float* __restrict__ b,
                                                float* __restrict__ o) {
  int i = blockIdx.x * 256 + threadIdx.x;  // 4096 total
  o[i] = a[i] + b[i];
}

// ---------- phase 1: xproj = x @ Wx^T, written PERMUTED for the lstm reader ----------
// C layout: [t(512)][hs(128)][brow(64)][jj(8)][gate(4)]
__global__ __launch_bounds__(256) void gemm_xproj(const u16* __restrict__ A,
                                                  const u16* __restrict__ Bw,
                                                  u16* __restrict__ C) {
  __shared__ __align__(16) u16 As[128 * 64];
  __shared__ __align__(16) u16 Bs[128 * 64];
  int wg = blockIdx.x;
  int swz = (wg & 7) * 1024 + (wg >> 3);  // XCD-aware bijective (8192 % 8 == 0)
  int mb = swz >> 5;
  int nb = swz & 31;
  int tid = threadIdx.x;
  int lane = tid & 63;
  int w = tid >> 6;
  int wm = w >> 1, wn = w & 1;

  int srow = lane >> 3;
  int scol = (lane & 7) * 8;
  const u16* Abase = A + (size_t)(mb * 128) * 1024;
  const u16* Bbase = Bw + (size_t)(nb * 128) * 1024;

  f32x4 acc[4][4];
#pragma unroll
  for (int i = 0; i < 4; ++i)
#pragma unroll
    for (int j = 0; j < 4; ++j) acc[i][j] = f32x4{0.f, 0.f, 0.f, 0.f};

  for (int k0 = 0; k0 < 1024; k0 += 64) {
#pragma unroll
    for (int r = 0; r < 4; ++r) {
      int chunk = w * 4 + r;
      int row = chunk * 8 + srow;
      __builtin_amdgcn_global_load_lds((gas1_t)(const void*)(Abase + (size_t)row * 1024 + k0 + scol),
                                       (las3_t)(void*)(&As[chunk * 512]), 16, 0, 0);
      __builtin_amdgcn_global_load_lds((gas1_t)(const void*)(Bbase + (size_t)row * 1024 + k0 + scol),
                                       (las3_t)(void*)(&Bs[chunk * 512]), 16, 0, 0);
    }
    __syncthreads();
#pragma unroll
    for (int kk = 0; kk < 64; kk += 32) {
      bf16x8 af[4], bfr[4];
#pragma unroll
      for (int mt = 0; mt < 4; ++mt)
        af[mt] = *(const bf16x8*)&As[(wm * 64 + mt * 16 + (lane & 15)) * 64 + kk + ((lane >> 4) << 3)];
#pragma unroll
      for (int nt = 0; nt < 4; ++nt)
        bfr[nt] = *(const bf16x8*)&Bs[(wn * 64 + nt * 16 + (lane & 15)) * 64 + kk + ((lane >> 4) << 3)];
#pragma unroll
      for (int mt = 0; mt < 4; ++mt)
#pragma unroll
        for (int nt = 0; nt < 4; ++nt)
          acc[mt][nt] = __builtin_amdgcn_mfma_f32_16x16x32_bf16(af[mt], bfr[nt], acc[mt][nt], 0, 0, 0);
    }
    __syncthreads();
  }
  int crowbase = mb * 128 + wm * 64;
  int ccolbase = nb * 128 + wn * 64;
#pragma unroll
  for (int mt = 0; mt < 4; ++mt)
#pragma unroll
    for (int nt = 0; nt < 4; ++nt) {
      int col = ccolbase + nt * 16 + (lane & 15);
      int gate = col >> 10;
      int hc = col & 1023;
      size_t cb = (size_t)(hc >> 3) * 2048 + (size_t)(hc & 7) * 4 + gate;  // hs*64*32 + jj*4 + gate
#pragma unroll
      for (int r = 0; r < 4; ++r) {
        int row = crowbase + mt * 16 + ((lane >> 4) << 2) + r;
        C[(size_t)(row >> 6) * 262144 + cb + (size_t)(row & 63) * 32] = f2bf(acc[mt][nt][r]);
      }
    }
}

// ---------- phase 2: persistent sequential LSTM ----------
// 128 WGs x 512 threads (8 waves = 2 gate-groups x 4 K-slices).
// WG = (bh, hw): batch-half bh (32 rows) x 16 h-cols (hw in 0..63 -> FULL
// 1024-col coverage per half; R7's bug was hw&31). Two independent 64-WG
// barrier domains (half of R2's 128). R2-proven protocol: sc0sc1 batched h
// loads, per-thread write-through h stores, vmcnt drain -> sync -> tid0 flag
// -> wave-0-only poll -> sync.
__global__ __launch_bounds__(512, 2) void lstm_seq(const u16* __restrict__ xprojP,
                                                   const u16* __restrict__ Whb,
                                                   const float* __restrict__ bias,
                                                   u16* __restrict__ hbuf,
                                                   u32* __restrict__ flags,
                                                   float* __restrict__ out) {
  __shared__ float pacc[32 * 272];  // 32 frags [cg][kq][m][cf], rows padded to 17
#define PIDX(frag, row, col) (((frag) * 272) + (row) * 17 + (col))
  int wg = blockIdx.x;     // 0..127
  int bh = wg >> 6;        // batch half (independent barrier domain)
  int hw = wg & 63;        // 16-col slice index (0..63 -> cols 0..1023)
  int tid = threadIdx.x;   // 0..511
  int lane = tid & 63;
  int w = tid >> 6;        // 0..7
  int cg = w >> 2;         // gate-group: 0 -> gates 0,1 ; 1 -> gates 2,3
  int kq = w & 3;          // K-slice
  int kw = kq << 8;        // k base (256 per K-slice)
  int hi8 = (lane >> 4) << 3;

  // preload Wh fragments (register-resident for all 512 steps)
  // wf[cf][ks]: gate = cg*2+cf, out-col = hw*16 + (lane&15)
  bf16x8 wf[2][8];
#pragma unroll
  for (int cf = 0; cf < 2; ++cf) {
    int wrow = ((cg * 2 + cf) << 10) + (hw << 4) + (lane & 15);
#pragma unroll
    for (int ks = 0; ks < 8; ++ks)
      wf[cf][ks] = *(const bf16x8*)&Whb[(size_t)wrow * 1024 + kw + ks * 32 + hi8];
  }

  int b = tid >> 4;                  // 0..31 batch row within half
  int jj = tid & 15;                 // 0..15 h-col within WG slice
  int hrow = (bh << 5) + b;
  int hcol = (hw << 4) + jj;
  float bs0 = bias[hcol], bs1 = bias[1024 + hcol], bs2 = bias[2048 + hcol], bs3 = bias[3072 + hcol];
  float c_state = 0.f;
  int am_row0 = (bh << 5) + (lane & 15);
  int am_row1 = am_row0 + 16;
  int mI = b >> 4, r16 = b & 15;
  u32* myflags = flags + (bh << 6);  // 64 dwords for this half

  // permuted xproj pointer; per-step stride 262144 elems (512 KB)
  const u16* xpt = xprojP + ((size_t)(hcol >> 3) * 64 + hrow) * 32 + (hcol & 7) * 4;
  u32x2 pd = *(const u32x2*)xpt;     // t=0 prefetch (plain cached)

  for (int t = 0; t < T_LEN; ++t) {
    const u16* hcur = hbuf + (size_t)(t & 1) * 65536;
    // --- coherent h load: 16x dwordx4 sc0 sc1 + vmcnt(0) in ONE asm ---
    const u16* p0 = hcur + (size_t)am_row0 * 1024 + kw + hi8;
    const u16* p1 = hcur + (size_t)am_row1 * 1024 + kw + hi8;
    u32x4 r0, r1, r2, r3, r4, r5, r6, r7, r8, r9, r10, r11, r12, r13, r14, r15;
    asm volatile(
        "global_load_dwordx4 %0, %16, off sc0 sc1\n\t"
        "global_load_dwordx4 %1, %16, off offset:64 sc0 sc1\n\t"
        "global_load_dwordx4 %2, %16, off offset:128 sc0 sc1\n\t"
        "global_load_dwordx4 %3, %16, off offset:192 sc0 sc1\n\t"
        "global_load_dwordx4 %4, %16, off offset:256 sc0 sc1\n\t"
        "global_load_dwordx4 %5, %16, off offset:320 sc0 sc1\n\t"
        "global_load_dwordx4 %6, %16, off offset:384 sc0 sc1\n\t"
        "global_load_dwordx4 %7, %16, off offset:448 sc0 sc1\n\t"
        "global_load_dwordx4 %8, %17, off sc0 sc1\n\t"
        "global_load_dwordx4 %9, %17, off offset:64 sc0 sc1\n\t"
        "global_load_dwordx4 %10, %17, off offset:128 sc0 sc1\n\t"
        "global_load_dwordx4 %11, %17, off offset:192 sc0 sc1\n\t"
        "global_load_dwordx4 %12, %17, off offset:256 sc0 sc1\n\t"
        "global_load_dwordx4 %13, %17, off offset:320 sc0 sc1\n\t"
        "global_load_dwordx4 %14, %17, off offset:384 sc0 sc1\n\t"
        "global_load_dwordx4 %15, %17, off offset:448 sc0 sc1\n\t"
        "s_waitcnt vmcnt(0)"
        : "=&v"(r0), "=&v"(r1), "=&v"(r2), "=&v"(r3),
          "=&v"(r4), "=&v"(r5), "=&v"(r6), "=&v"(r7),
          "=&v"(r8), "=&v"(r9), "=&v"(r10), "=&v"(r11),
          "=&v"(r12), "=&v"(r13), "=&v"(r14), "=&v"(r15)
        : "v"(p0), "v"(p1)
        : "memory");
    bf16x8 a0s[8] = {__builtin_bit_cast(bf16x8, r0),  __builtin_bit_cast(bf16x8, r1),
                     __builtin_bit_cast(bf16x8, r2),  __builtin_bit_cast(bf16x8, r3),
                     __builtin_bit_cast(bf16x8, r4),  __builtin_bit_cast(bf16x8, r5),
                     __builtin_bit_cast(bf16x8, r6),  __builtin_bit_cast(bf16x8, r7)};
    bf16x8 a1s[8] = {__builtin_bit_cast(bf16x8, r8),  __builtin_bit_cast(bf16x8, r9),
                     __builtin_bit_cast(bf16x8, r10), __builtin_bit_cast(bf16x8, r11),
                     __builtin_bit_cast(bf16x8, r12), __builtin_bit_cast(bf16x8, r13),
                     __builtin_bit_cast(bf16x8, r14), __builtin_bit_cast(bf16x8, r15)};

    f32x4 acc00 = f32x4{0.f, 0.f, 0.f, 0.f}, acc01 = acc00, acc10 = acc00, acc11 = acc00;
#pragma unroll
    for (int ks = 0; ks < 8; ++ks) {
      acc00 = __builtin_amdgcn_mfma_f32_16x16x32_bf16(a0s[ks], wf[0][ks], acc00, 0, 0, 0);
      acc01 = __builtin_amdgcn_mfma_f32_16x16x32_bf16(a0s[ks], wf[1][ks], acc01, 0, 0, 0);
      acc10 = __builtin_amdgcn_mfma_f32_16x16x32_bf16(a1s[ks], wf[0][ks], acc10, 0, 0, 0);
      acc11 = __builtin_amdgcn_mfma_f32_16x16x32_bf16(a1s[ks], wf[1][ks], acc11, 0, 0, 0);
    }
    // per-wave partials -> LDS: frag = cg*16 + kq*4 + m*2 + cf
    {
      int rbase = ((lane >> 4) << 2);
      int cidx = lane & 15;
      int f0i = (cg << 4) + (kq << 2);
#pragma unroll
      for (int r = 0; r < 4; ++r) {
        pacc[PIDX(f0i + 0, rbase + r, cidx)] = acc00[r];
        pacc[PIDX(f0i + 1, rbase + r, cidx)] = acc01[r];
        pacc[PIDX(f0i + 2, rbase + r, cidx)] = acc10[r];
        pacc[PIDX(f0i + 3, rbase + r, cidx)] = acc11[r];
      }
    }
    __syncthreads();
    float g[4];
#pragma unroll
    for (int gate = 0; gate < 4; ++gate) {
      int cgg = gate >> 1, cf = gate & 1;
      float s = 0.f;
#pragma unroll
      for (int k2 = 0; k2 < 4; ++k2)
        s += pacc[PIDX((cgg << 4) + (k2 << 2) + (mI << 1) + cf, r16, jj)];
      g[gate] = s;
    }
    // tie the prefetched xproj dwords to a vmcnt before use (rule #18)
    asm volatile("s_waitcnt vmcnt(0)" : "+v"(pd));
    float gi = g[0] + bf2f((u16)(pd[0] & 0xFFFFu)) + bs0;
    float gf = g[1] + bf2f((u16)(pd[0] >> 16)) + bs1;
    float go = g[2] + bf2f((u16)(pd[1] & 0xFFFFu)) + bs2;
    float gc = g[3] + bf2f((u16)(pd[1] >> 16)) + bs3;
    float iv = 1.f / (1.f + __expf(-gi));
    float fv = 1.f / (1.f + __expf(-gf));
    float ov = 1.f / (1.f + __expf(-go));
    float cv = tanhf(gc);
    c_state = 1.f / (1.f + __expf(-(fv * c_state + iv * cv)));  // nonstandard, per reference
    float hn = tanhf(c_state) * ov;

    if (t == T_LEN - 1) {
      out[(size_t)hrow * 1024 + hcol] = hn;
    } else {
      // h store (write-through) + xproj(t+1) prefetch + in-order counted drain:
      // vmcnt(1) retires the OLDER store; the load stays in flight through the poll.
      u16* hdst = hbuf + (size_t)((t & 1) ^ 1) * 65536 + (size_t)hrow * 1024 + hcol;
      const u16* xnext = xpt + (size_t)(t + 1) * 262144;
      u32 hb = (u32)f2bf(hn);
      asm volatile(
          "global_store_short %1, %3, off sc0 sc1\n\t"
          "global_load_dwordx2 %0, %2, off\n\t"
          "s_waitcnt vmcnt(1)"
          : "=&v"(pd)
          : "v"(hdst), "v"(xnext), "v"(hb)
          : "memory");
      __syncthreads();  // all 8 waves' stores drained; pacc reads done
      u32 tgt = (u32)(t + 1);
      if (tid == 0) {
        u32* fp = myflags + hw;
        asm volatile("global_store_dword %0, %1, off sc0 sc1" :: "v"(fp), "v"(tgt) : "memory");
      }
      if (tid < 64) {
        const u32* fp = myflags + lane;  // 64 flags, 4 LLC lines
        for (;;) {
          u32 f;
          asm volatile("global_load_dword %0, %1, off sc0 sc1\n\ts_waitcnt vmcnt(0)"
                       : "=v"(f) : "v"(fp) : "memory");
          if (__all(f >= tgt)) break;
        }
      }
      __syncthreads();
    }
  }
}

extern "C" void kernel_launch(void* const* d_in, const int* in_sizes, int n_in,
                              void* d_out, int out_size, void* d_ws, size_t ws_size,
                              hipStream_t stream) {
  const float* x  = (const float*)d_in[0];   // [512][64][1024]
  const float* Wx = (const float*)d_in[1];   // [4][1024][1024]
  const float* bx = (const float*)d_in[2];   // [4][1024]
  const float* Wh = (const float*)d_in[3];   // [4][1024][1024]
  const float* bh = (const float*)d_in[4];   // [4][1024]
  float* out = (float*)d_out;                // [64][1024]
  char* ws = (char*)d_ws;

  u16* wx_bf  = (u16*)(ws + OFF_WX);
  u16* wh_bf  = (u16*)(ws + OFF_WH);
  float* bias = (float*)(ws + OFF_BIAS);
  u32* flags  = (u32*)(ws + OFF_FLAGS);
  u16* hbuf   = (u16*)(ws + OFF_HBUF);
  u16* x_bf   = (u16*)(ws + OFF_XBF);
  u16* xproj  = (u16*)(ws + OFF_XPROJ);

  // per-launch: zero flags (1 KiB) + hbuf slot 0 (h_0 = 0, 128 KiB) -- contiguous
  hipMemsetAsync(ws + OFF_FLAGS, 0, 1024 + 131072, stream);

  cvt_f32_bf16<<<4096, 256, 0, stream>>>(Wx, wx_bf, 4194304);
  cvt_f32_bf16<<<4096, 256, 0, stream>>>(Wh, wh_bf, 4194304);
  bias_add<<<16, 256, 0, stream>>>(bx, bh, bias);
  cvt_f32_bf16<<<32768, 256, 0, stream>>>(x, x_bf, 33554432);
  gemm_xproj<<<8192, 256, 0, stream>>>(x_bf, wx_bf, xproj);
  lstm_seq<<<128, 512, 0, stream>>>(xproj, wh_bf, bias, hbuf, flags, out);
}

// Round 9
// 4224.754 us; speedup vs baseline: 1.6857x; 1.0880x over previous
//
#include <hip/hip_runtime.h>

typedef unsigned short u16;
typedef unsigned int u32;
typedef __attribute__((ext_vector_type(8))) short bf16x8;
typedef __attribute__((ext_vector_type(4))) float f32x4;
typedef __attribute__((ext_vector_type(2))) u32 u32x2;
typedef __attribute__((ext_vector_type(4))) u32 u32x4;
typedef const __attribute__((address_space(1))) void* gas1_t;
typedef __attribute__((address_space(3))) void* las3_t;

// Problem dims
#define T_LEN 512
#define B_SZ  64
#define D_SZ  1024
#define H_SZ  1024

// workspace layout (bytes), all 256-aligned
#define OFF_WX    0UL           // 8 MiB  bf16 Wx  [4096][1024]
#define OFF_WH    8388608UL     // 8 MiB  bf16 Wh  [4096][1024]
#define OFF_BIAS  16777216UL    // 16 KiB f32 bias[4096] = bx+bh
#define OFF_FLAGS 16793600UL    // 1 KiB: u32 cnt0 @ +0, u32 cnt1 @ +256 (per-half barrier counters)
#define OFF_HBUF  16794624UL    // 256 KiB bf16 hbuf[2][64][1024]
#define OFF_XBF   17056768UL    // 64 MiB bf16 x [32768][1024]
#define OFF_XPROJ 84165632UL    // 256 MiB bf16 xprojP [512][128][64][8][4] ([t][hs][brow][jj][gate])

__device__ __forceinline__ u16 f2bf(float f) {
  u32 u = __builtin_bit_cast(u32, f);
  u += 0x7FFFu + ((u >> 16) & 1u);   // RNE
  return (u16)(u >> 16);
}
__device__ __forceinline__ float bf2f(u16 h) {
  u32 u = ((u32)h) << 16;
  return __builtin_bit_cast(float, u);
}

// ---------- phase 0: conversions ----------
__global__ __launch_bounds__(256) void cvt_f32_bf16(const float* __restrict__ in,
                                                    u16* __restrict__ out, int n) {
  int i = (blockIdx.x * 256 + threadIdx.x) * 4;
  if (i >= n) return;
  float4 v = *(const float4*)(in + i);
  ushort4 o;
  o.x = f2bf(v.x); o.y = f2bf(v.y); o.z = f2bf(v.z); o.w = f2bf(v.w);
  *(ushort4*)(out + i) = o;
}

__global__ __launch_bounds__(256) void bias_add(const float* __restrict__ a,
                                                const float* __restrict__ b,
                                                float* __restrict__ o) {
  int i = blockIdx.x * 256 + threadIdx.x;  // 4096 total
  o[i] = a[i] + b[i];
}

// ---------- phase 1: xproj = x @ Wx^T, written PERMUTED for the lstm reader ----------
// C layout: [t(512)][hs(128)][brow(64)][jj(8)][gate(4)]
__global__ __launch_bounds__(256) void gemm_xproj(const u16* __restrict__ A,
                                                  const u16* __restrict__ Bw,
                                                  u16* __restrict__ C) {
  __shared__ __align__(16) u16 As[128 * 64];
  __shared__ __align__(16) u16 Bs[128 * 64];
  int wg = blockIdx.x;
  int swz = (wg & 7) * 1024 + (wg >> 3);  // XCD-aware bijective (8192 % 8 == 0)
  int mb = swz >> 5;
  int nb = swz & 31;
  int tid = threadIdx.x;
  int lane = tid & 63;
  int w = tid >> 6;
  int wm = w >> 1, wn = w & 1;

  int srow = lane >> 3;
  int scol = (lane & 7) * 8;
  const u16* Abase = A + (size_t)(mb * 128) * 1024;
  const u16* Bbase = Bw + (size_t)(nb * 128) * 1024;

  f32x4 acc[4][4];
#pragma unroll
  for (int i = 0; i < 4; ++i)
#pragma unroll
    for (int j = 0; j < 4; ++j) acc[i][j] = f32x4{0.f, 0.f, 0.f, 0.f};

  for (int k0 = 0; k0 < 1024; k0 += 64) {
#pragma unroll
    for (int r = 0; r < 4; ++r) {
      int chunk = w * 4 + r;
      int row = chunk * 8 + srow;
      __builtin_amdgcn_global_load_lds((gas1_t)(const void*)(Abase + (size_t)row * 1024 + k0 + scol),
                                       (las3_t)(void*)(&As[chunk * 512]), 16, 0, 0);
      __builtin_amdgcn_global_load_lds((gas1_t)(const void*)(Bbase + (size_t)row * 1024 + k0 + scol),
                                       (las3_t)(void*)(&Bs[chunk * 512]), 16, 0, 0);
    }
    __syncthreads();
#pragma unroll
    for (int kk = 0; kk < 64; kk += 32) {
      bf16x8 af[4], bfr[4];
#pragma unroll
      for (int mt = 0; mt < 4; ++mt)
        af[mt] = *(const bf16x8*)&As[(wm * 64 + mt * 16 + (lane & 15)) * 64 + kk + ((lane >> 4) << 3)];
#pragma unroll
      for (int nt = 0; nt < 4; ++nt)
        bfr[nt] = *(const bf16x8*)&Bs[(wn * 64 + nt * 16 + (lane & 15)) * 64 + kk + ((lane >> 4) << 3)];
#pragma unroll
      for (int mt = 0; mt < 4; ++mt)
#pragma unroll
        for (int nt = 0; nt < 4; ++nt)
          acc[mt][nt] = __builtin_amdgcn_mfma_f32_16x16x32_bf16(af[mt], bfr[nt], acc[mt][nt], 0, 0, 0);
    }
    __syncthreads();
  }
  int crowbase = mb * 128 + wm * 64;
  int ccolbase = nb * 128 + wn * 64;
#pragma unroll
  for (int mt = 0; mt < 4; ++mt)
#pragma unroll
    for (int nt = 0; nt < 4; ++nt) {
      int col = ccolbase + nt * 16 + (lane & 15);
      int gate = col >> 10;
      int hc = col & 1023;
      size_t cb = (size_t)(hc >> 3) * 2048 + (size_t)(hc & 7) * 4 + gate;  // hs*64*32 + jj*4 + gate
#pragma unroll
      for (int r = 0; r < 4; ++r) {
        int row = crowbase + mt * 16 + ((lane >> 4) << 2) + r;
        C[(size_t)(row >> 6) * 262144 + cb + (size_t)(row & 63) * 32] = f2bf(acc[mt][nt][r]);
      }
    }
}

// ---------- phase 2: persistent sequential LSTM ----------
// 128 WGs x 512 threads (8 waves = 2 gate-groups x 4 K-slices).
// WG = (bh, hw): batch-half bh (32 rows) x 16 h-cols. Two independent 64-WG
// barrier domains. Barrier = ONE LLC-point atomic counter per domain:
// publish = fire-and-forget global_atomic_add(+1); poll = tid0-only
// global_atomic_add(+0) sc0 (atomic read AT the LLC -- line stays resident,
// no HBM miss, unlike sc0sc1 flag stores which invalidate the LLC line and
// push every poll round to HBM latency; that was R8's ~8 HBM rounds/step).
// h transport unchanged from R8 (proven): sc0sc1 batched loads, per-thread
// write-through stores, vmcnt drain -> sync -> publish -> poll -> sync.
__global__ __launch_bounds__(512, 2) void lstm_seq(const u16* __restrict__ xprojP,
                                                   const u16* __restrict__ Whb,
                                                   const float* __restrict__ bias,
                                                   u16* __restrict__ hbuf,
                                                   u32* __restrict__ flags,
                                                   float* __restrict__ out) {
  __shared__ float pacc[32 * 272];  // 32 frags [cg][kq][m][cf], rows padded to 17
#define PIDX(frag, row, col) (((frag) * 272) + (row) * 17 + (col))
  int wg = blockIdx.x;     // 0..127
  int bh = wg >> 6;        // batch half (independent barrier domain)
  int hw = wg & 63;        // 16-col slice index (0..63 -> cols 0..1023)
  int tid = threadIdx.x;   // 0..511
  int lane = tid & 63;
  int w = tid >> 6;        // 0..7
  int cg = w >> 2;         // gate-group: 0 -> gates 0,1 ; 1 -> gates 2,3
  int kq = w & 3;          // K-slice
  int kw = kq << 8;        // k base (256 per K-slice)
  int hi8 = (lane >> 4) << 3;

  // preload Wh fragments (register-resident for all 512 steps)
  bf16x8 wf[2][8];
#pragma unroll
  for (int cf = 0; cf < 2; ++cf) {
    int wrow = ((cg * 2 + cf) << 10) + (hw << 4) + (lane & 15);
#pragma unroll
    for (int ks = 0; ks < 8; ++ks)
      wf[cf][ks] = *(const bf16x8*)&Whb[(size_t)wrow * 1024 + kw + ks * 32 + hi8];
  }

  int b = tid >> 4;                  // 0..31 batch row within half
  int jj = tid & 15;                 // 0..15 h-col within WG slice
  int hrow = (bh << 5) + b;
  int hcol = (hw << 4) + jj;
  float bs0 = bias[hcol], bs1 = bias[1024 + hcol], bs2 = bias[2048 + hcol], bs3 = bias[3072 + hcol];
  float c_state = 0.f;
  int am_row0 = (bh << 5) + (lane & 15);
  int am_row1 = am_row0 + 16;
  int mI = b >> 4, r16 = b & 15;
  u32* cnt = flags + (bh << 6);      // per-half counter, 256 B apart

  // permuted xproj pointer; per-step stride 262144 elems (512 KB)
  const u16* xpt = xprojP + ((size_t)(hcol >> 3) * 64 + hrow) * 32 + (hcol & 7) * 4;
  u32x2 pd = *(const u32x2*)xpt;     // t=0 prefetch (plain cached)

  for (int t = 0; t < T_LEN; ++t) {
    const u16* hcur = hbuf + (size_t)(t & 1) * 65536;
    // --- coherent h load: 16x dwordx4 sc0 sc1 + vmcnt(0) in ONE asm ---
    const u16* p0 = hcur + (size_t)am_row0 * 1024 + kw + hi8;
    const u16* p1 = hcur + (size_t)am_row1 * 1024 + kw + hi8;
    u32x4 r0, r1, r2, r3, r4, r5, r6, r7, r8, r9, r10, r11, r12, r13, r14, r15;
    asm volatile(
        "global_load_dwordx4 %0, %16, off sc0 sc1\n\t"
        "global_load_dwordx4 %1, %16, off offset:64 sc0 sc1\n\t"
        "global_load_dwordx4 %2, %16, off offset:128 sc0 sc1\n\t"
        "global_load_dwordx4 %3, %16, off offset:192 sc0 sc1\n\t"
        "global_load_dwordx4 %4, %16, off offset:256 sc0 sc1\n\t"
        "global_load_dwordx4 %5, %16, off offset:320 sc0 sc1\n\t"
        "global_load_dwordx4 %6, %16, off offset:384 sc0 sc1\n\t"
        "global_load_dwordx4 %7, %16, off offset:448 sc0 sc1\n\t"
        "global_load_dwordx4 %8, %17, off sc0 sc1\n\t"
        "global_load_dwordx4 %9, %17, off offset:64 sc0 sc1\n\t"
        "global_load_dwordx4 %10, %17, off offset:128 sc0 sc1\n\t"
        "global_load_dwordx4 %11, %17, off offset:192 sc0 sc1\n\t"
        "global_load_dwordx4 %12, %17, off offset:256 sc0 sc1\n\t"
        "global_load_dwordx4 %13, %17, off offset:320 sc0 sc1\n\t"
        "global_load_dwordx4 %14, %17, off offset:384 sc0 sc1\n\t"
        "global_load_dwordx4 %15, %17, off offset:448 sc0 sc1\n\t"
        "s_waitcnt vmcnt(0)"
        : "=&v"(r0), "=&v"(r1), "=&v"(r2), "=&v"(r3),
          "=&v"(r4), "=&v"(r5), "=&v"(r6), "=&v"(r7),
          "=&v"(r8), "=&v"(r9), "=&v"(r10), "=&v"(r11),
          "=&v"(r12), "=&v"(r13), "=&v"(r14), "=&v"(r15)
        : "v"(p0), "v"(p1)
        : "memory");
    bf16x8 a0s[8] = {__builtin_bit_cast(bf16x8, r0),  __builtin_bit_cast(bf16x8, r1),
                     __builtin_bit_cast(bf16x8, r2),  __builtin_bit_cast(bf16x8, r3),
                     __builtin_bit_cast(bf16x8, r4),  __builtin_bit_cast(bf16x8, r5),
                     __builtin_bit_cast(bf16x8, r6),  __builtin_bit_cast(bf16x8, r7)};
    bf16x8 a1s[8] = {__builtin_bit_cast(bf16x8, r8),  __builtin_bit_cast(bf16x8, r9),
                     __builtin_bit_cast(bf16x8, r10), __builtin_bit_cast(bf16x8, r11),
                     __builtin_bit_cast(bf16x8, r12), __builtin_bit_cast(bf16x8, r13),
                     __builtin_bit_cast(bf16x8, r14), __builtin_bit_cast(bf16x8, r15)};

    f32x4 acc00 = f32x4{0.f, 0.f, 0.f, 0.f}, acc01 = acc00, acc10 = acc00, acc11 = acc00;
#pragma unroll
    for (int ks = 0; ks < 8; ++ks) {
      acc00 = __builtin_amdgcn_mfma_f32_16x16x32_bf16(a0s[ks], wf[0][ks], acc00, 0, 0, 0);
      acc01 = __builtin_amdgcn_mfma_f32_16x16x32_bf16(a0s[ks], wf[1][ks], acc01, 0, 0, 0);
      acc10 = __builtin_amdgcn_mfma_f32_16x16x32_bf16(a1s[ks], wf[0][ks], acc10, 0, 0, 0);
      acc11 = __builtin_amdgcn_mfma_f32_16x16x32_bf16(a1s[ks], wf[1][ks], acc11, 0, 0, 0);
    }
    // per-wave partials -> LDS: frag = cg*16 + kq*4 + m*2 + cf
    {
      int rbase = ((lane >> 4) << 2);
      int cidx = lane & 15;
      int f0i = (cg << 4) + (kq << 2);
#pragma unroll
      for (int r = 0; r < 4; ++r) {
        pacc[PIDX(f0i + 0, rbase + r, cidx)] = acc00[r];
        pacc[PIDX(f0i + 1, rbase + r, cidx)] = acc01[r];
        pacc[PIDX(f0i + 2, rbase + r, cidx)] = acc10[r];
        pacc[PIDX(f0i + 3, rbase + r, cidx)] = acc11[r];
      }
    }
    __syncthreads();
    float g[4];
#pragma unroll
    for (int gate = 0; gate < 4; ++gate) {
      int cgg = gate >> 1, cf = gate & 1;
      float s = 0.f;
#pragma unroll
      for (int k2 = 0; k2 < 4; ++k2)
        s += pacc[PIDX((cgg << 4) + (k2 << 2) + (mI << 1) + cf, r16, jj)];
      g[gate] = s;
    }
    // tie the prefetched xproj dwords to a vmcnt before use (rule #18)
    asm volatile("s_waitcnt vmcnt(0)" : "+v"(pd));
    float gi = g[0] + bf2f((u16)(pd[0] & 0xFFFFu)) + bs0;
    float gf = g[1] + bf2f((u16)(pd[0] >> 16)) + bs1;
    float go = g[2] + bf2f((u16)(pd[1] & 0xFFFFu)) + bs2;
    float gc = g[3] + bf2f((u16)(pd[1] >> 16)) + bs3;
    float iv = 1.f / (1.f + __expf(-gi));
    float fv = 1.f / (1.f + __expf(-gf));
    float ov = 1.f / (1.f + __expf(-go));
    float cv = tanhf(gc);
    c_state = 1.f / (1.f + __expf(-(fv * c_state + iv * cv)));  // nonstandard, per reference
    float hn = tanhf(c_state) * ov;

    if (t == T_LEN - 1) {
      out[(size_t)hrow * 1024 + hcol] = hn;
    } else {
      // h store (write-through) + xproj(t+1) prefetch + in-order counted drain:
      // vmcnt(1) retires the OLDER store; the load stays in flight through the poll.
      u16* hdst = hbuf + (size_t)((t & 1) ^ 1) * 65536 + (size_t)hrow * 1024 + hcol;
      const u16* xnext = xpt + (size_t)(t + 1) * 262144;
      u32 hb = (u32)f2bf(hn);
      asm volatile(
          "global_store_short %1, %3, off sc0 sc1\n\t"
          "global_load_dwordx2 %0, %2, off\n\t"
          "s_waitcnt vmcnt(1)"
          : "=&v"(pd)
          : "v"(hdst), "v"(xnext), "v"(hb)
          : "memory");
      __syncthreads();  // all 8 waves' stores drained; pacc reads done
      // publish: fire-and-forget atomic increment (performed at the LLC)
      if (tid == 0) {
        u32 one = 1u;
        asm volatile("global_atomic_add %0, %1, off" :: "v"(cnt), "v"(one) : "memory");
        // poll: atomic read-at-LLC (add 0, sc0 returns old). One line, LLC-resident.
        u32 tgt64 = (u32)((t + 1) << 6);
        u32 zero = 0u;
        u32 old;
        for (;;) {
          asm volatile("global_atomic_add %0, %1, %2, off sc0\n\ts_waitcnt vmcnt(0)"
                       : "=&v"(old) : "v"(cnt), "v"(zero) : "memory");
          if (old >= tgt64) break;
        }
      }
      __syncthreads();
    }
  }
}

extern "C" void kernel_launch(void* const* d_in, const int* in_sizes, int n_in,
                              void* d_out, int out_size, void* d_ws, size_t ws_size,
                              hipStream_t stream) {
  const float* x  = (const float*)d_in[0];   // [512][64][1024]
  const float* Wx = (const float*)d_in[1];   // [4][1024][1024]
  const float* bx = (const float*)d_in[2];   // [4][1024]
  const float* Wh = (const float*)d_in[3];   // [4][1024][1024]
  const float* bh = (const float*)d_in[4];   // [4][1024]
  float* out = (float*)d_out;                // [64][1024]
  char* ws = (char*)d_ws;

  u16* wx_bf  = (u16*)(ws + OFF_WX);
  u16* wh_bf  = (u16*)(ws + OFF_WH);
  float* bias = (float*)(ws + OFF_BIAS);
  u32* flags  = (u32*)(ws + OFF_FLAGS);
  u16* hbuf   = (u16*)(ws + OFF_HBUF);
  u16* x_bf   = (u16*)(ws + OFF_XBF);
  u16* xproj  = (u16*)(ws + OFF_XPROJ);

  // per-launch: zero counters (1 KiB) + hbuf slot 0 (h_0 = 0, 128 KiB) -- contiguous
  hipMemsetAsync(ws + OFF_FLAGS, 0, 1024 + 131072, stream);

  cvt_f32_bf16<<<4096, 256, 0, stream>>>(Wx, wx_bf, 4194304);
  cvt_f32_bf16<<<4096, 256, 0, stream>>>(Wh, wh_bf, 4194304);
  bias_add<<<16, 256, 0, stream>>>(bx, bh, bias);
  cvt_f32_bf16<<<32768, 256, 0, stream>>>(x, x_bf, 33554432);
  gemm_xproj<<<8192, 256, 0, stream>>>(x_bf, wx_bf, xproj);
  lstm_seq<<<128, 512, 0, stream>>>(xproj, wh_bf, bias, hbuf, flags, out);
}